// Round 12
// baseline (271.171 us; speedup 1.0000x reference)
//
#include <hip/hip_runtime.h>

#define N_SAMP   1024
#define IN_F     512
#define OUT_F    512
#define N_HEADS  32
#define N_SPLITS 4
#define N_GROUPS (N_HEADS * N_SPLITS)
#define DELTA_SCALE 0.1f

// R16: R12 (best verified, ~78 us kernel) + RING-3 PREFETCH (distance 2)
// + launch_bounds(256,2) to lift the VGPR cap to 128 (law: cap = 256/arg2,
// pinned on 7 data points R7-R14).
//
// Model discrimination: supply has been flat ~3.4 TB/s logical across
// 8/16/32 waves/CU and 128B-1KB segments (R7-R15). Two surviving models:
//   (a) per-CU outstanding-line limit x 128B / L3-latency -> structural
//       ceiling, nothing source-level helps;
//   (b) latency-limited with prefetch distance 1: dist-1 dbuf hides only
//       ~312 VALU cyc of the ~600-900 cyc L3/HBM latency -> ~300-600 cyc
//       exposed stall per step x 16 steps = the whole runtime. Every
//       structure so far was dist-1.
// This kernel deepens the pipeline to distance 2 (ring of 3 stages, 48
// VGPR for W/D buffers) with everything else IDENTICAL to R12: J=16,
// 64-col tiles, KQ=8, nt-D loads, nt stores, 1024 blocks, 16 waves/CU.
// Full unroll keeps all ring indices compile-time (no dynamic-index
// scratch). If (b): 45-60 us. If flat: (a) confirmed -> plateau.

typedef float f32x2 __attribute__((ext_vector_type(2)));

__device__ __forceinline__ f32x2 nt_load2(const float* p) {
    return __builtin_nontemporal_load((const f32x2*)p);
}
__device__ __forceinline__ void nt_store2(float* p, f32x2 v) {
    __builtin_nontemporal_store(v, (f32x2*)p);
}

__global__ __launch_bounds__(256, 2) void lms_fused_nt_r3(
    const float* __restrict__ X, const int* __restrict__ head_ix,
    const int* __restrict__ split_ix, const float* __restrict__ W,
    const float* __restrict__ D, const float* __restrict__ bias,
    float* __restrict__ out)
{
    constexpr int J    = 16;           // samples per chunk
    constexpr int KQ   = 8;            // k-split ways
    constexpr int KT   = IN_F / KQ;    // 64 k rows per thread
    constexpr int NST  = KT / 4;       // 16 steps of 4 rows
    constexpr int NOUT = (J * 32) / 256;  // 2

    __shared__ float buf[J * IN_F];    // Xs[J][512] <-> Red[KQ][J][32] float2
    __shared__ int   list[N_SAMP];
    __shared__ int   wsum[4];

    const int g    = blockIdx.y;           // combo = h*N_SPLITS + s
    const int h    = g >> 2;               // N_SPLITS == 4
    const int c0   = blockIdx.x * 64;
    const int tid  = threadIdx.x;
    const int c2   = tid & 31;             // col pair
    const int kq   = tid >> 5;             // k-eighth
    const int lane = tid & 63;
    const int wave = tid >> 6;

    // deterministic order-preserving compaction of samples matching combo g
    int run = 0;
    for (int r = 0; r < N_SAMP / 256; ++r) {
        const int i   = r * 256 + tid;
        const int key = head_ix[i] * N_SPLITS + split_ix[i];
        const bool hit = (key == g);
        const unsigned long long m = __ballot(hit);
        if (lane == 0) wsum[wave] = __popcll(m);
        __syncthreads();
        int base = run;
        for (int w = 0; w < 4; ++w)
            if (w < wave) base += wsum[w];
        if (hit)
            list[base + __popcll(m & ((1ULL << lane) - 1ULL))] = i;
        run += wsum[0] + wsum[1] + wsum[2] + wsum[3];
        __syncthreads();               // wsum consumed before next round
    }
    const int total = run;
    if (total == 0) return;            // block-uniform

    // thread's stripes: rows kq*KT .. kq*KT+63, cols c0+2*c2 (+1)
    const size_t roff = (size_t)(kq * KT) * OUT_F + c0 + c2 * 2;
    const float* wp = W + (size_t)h * (IN_F * OUT_F) + roff;
    const float* dp = D + (size_t)g * (IN_F * OUT_F) + roff;

    for (int s0 = 0; s0 < total; s0 += J) {
        const int nc = min(total - s0, J);

        __syncthreads();               // buf may still hold previous Red
        for (int i = tid; i < J * (IN_F / 4); i += 256) {
            const int s = i >> 7, q = i & 127;
            float4 v = make_float4(0.f, 0.f, 0.f, 0.f);
            if (s < nc)
                v = *(const float4*)(X + (size_t)list[s0 + s] * IN_F + q * 4);
            *(float4*)(&buf[s * IN_F + q * 4]) = v;
        }
        __syncthreads();

        float2 acc[J];
#pragma unroll
        for (int j = 0; j < J; ++j) { acc[j].x = 0.f; acc[j].y = 0.f; }

        // ring-3 software pipeline: stages t, t+1, t+2 in flight.
        // 24 float2 = 48 VGPR of W/D buffers; all indices compile-time
        // under the full unroll.
        float2 wb[3][4];
        f32x2  db[3][4];
#pragma unroll
        for (int p = 0; p < 2; ++p) {
            const float* wn = wp + (size_t)(p * 4) * OUT_F;
            const float* dn = dp + (size_t)(p * 4) * OUT_F;
#pragma unroll
            for (int u = 0; u < 4; ++u) {
                wb[p][u] = *(const float2*)(wn + (size_t)u * OUT_F);
                db[p][u] = nt_load2(dn + (size_t)u * OUT_F);
            }
        }

#pragma unroll
        for (int st = 0; st < NST; ++st) {
            const int lb = (st + 2) % 3;   // stage to fill   (static)
            const int cb = st % 3;         // stage to consume (static)
            if (st + 2 < NST) {
                const float* wn = wp + (size_t)((st + 2) * 4) * OUT_F;
                const float* dn = dp + (size_t)((st + 2) * 4) * OUT_F;
#pragma unroll
                for (int u = 0; u < 4; ++u) {
                    wb[lb][u] = *(const float2*)(wn + (size_t)u * OUT_F);
                    db[lb][u] = nt_load2(dn + (size_t)u * OUT_F);
                }
            }

            // combined weight for this 4-row batch
            float2 rc[4];
#pragma unroll
            for (int u = 0; u < 4; ++u) {
                rc[u].x = wb[cb][u].x + DELTA_SCALE * db[cb][u].x;
                rc[u].y = wb[cb][u].y + DELTA_SCALE * db[cb][u].y;
            }

            const float* xb = &buf[kq * KT + st * 4];
#pragma unroll
            for (int j = 0; j < J; ++j) {
                const float4 xv = *(const float4*)(xb + j * IN_F); // broadcast
                acc[j].x += xv.x * rc[0].x; acc[j].y += xv.x * rc[0].y;
                acc[j].x += xv.y * rc[1].x; acc[j].y += xv.y * rc[1].y;
                acc[j].x += xv.z * rc[2].x; acc[j].y += xv.z * rc[2].y;
                acc[j].x += xv.w * rc[3].x; acc[j].y += xv.w * rc[3].y;
            }
        }

        __syncthreads();               // Xs fully consumed; reuse buf as Red
        float2* Red = (float2*)buf;    // [KQ][J][32]
#pragma unroll
        for (int j = 0; j < J; ++j)
            Red[(kq * J + j) * 32 + c2] = acc[j];
        __syncthreads();

        // sole-owner epilogue: sum the 8 k-partials, add bias, nt store
#pragma unroll
        for (int t = 0; t < NOUT; ++t) {
            const int oi = t * 256 + tid;
            const int j = oi >> 5, cc = oi & 31;
            if (j < nc) {
                float2 s = make_float2(0.f, 0.f);
#pragma unroll
                for (int q = 0; q < KQ; ++q) {
                    const float2 r = Red[(q * J + j) * 32 + cc];
                    s.x += r.x; s.y += r.y;
                }
                const float2 bv =
                    *(const float2*)(bias + (size_t)h * OUT_F + c0 + cc * 2);
                float* op = out + (size_t)list[s0 + j] * OUT_F + c0 + cc * 2;
                f32x2 res;
                res.x = s.x + bv.x;
                res.y = s.y + bv.y;
                nt_store2(op, res);
            }
        }
    }
}

extern "C" void kernel_launch(void* const* d_in, const int* in_sizes, int n_in,
                              void* d_out, int out_size, void* d_ws, size_t ws_size,
                              hipStream_t stream) {
    const float* X        = (const float*)d_in[0];
    const int*   head_ix  = (const int*)d_in[1];
    const int*   split_ix = (const int*)d_in[2];
    const float* W        = (const float*)d_in[3];
    const float* D        = (const float*)d_in[4];
    const float* bias     = (const float*)d_in[5];
    float*       out      = (float*)d_out;

    // 128 combos x 8 col-tiles = 1024 blocks of 256 thr; LDS 36.9 KB ->
    // 4 blocks/CU x 4 waves = 16 waves/CU (same as R12). launch_bounds
    // (256,2) lifts the VGPR cap to 128 so the ring-3 pipeline (~107 VGPR)
    // fits without spills. Single dispatch; out written once, bias folded.
    dim3 gf(OUT_F / 64, N_GROUPS);
    lms_fused_nt_r3<<<gf, 256, 0, stream>>>(X, head_ix, split_ix, W, D, bias, out);
}

// Round 13
// 229.722 us; speedup vs baseline: 1.1804x; 1.1804x over previous
//
#include <hip/hip_runtime.h>

#define N_SAMP   1024
#define IN_F     512
#define OUT_F    512
#define N_HEADS  32
#define N_SPLITS 4
#define N_GROUPS (N_HEADS * N_SPLITS)
#define DELTA_SCALE 0.1f

// R17: last clean probe of the supply wall -- 16B/lane W/D requests on the
// R12 structure, budgeted to NOT spill (R13/R14/R16 all drowned in scratch).
//
// Evidence: unique-byte supply flat ~3.4 TB/s across waves (8/16/32),
// segment geometry, XCD pinning; nt = +10% (kept). Width 8->16B/lane has
// NEVER run unconfounded (R8 hinted 4.5 TB/s logical; R13/14 spilled).
// VGPR budget law: cap = 256/arg2; real pressure = naive + ~25 (R16).
// Design: J=12 -> acc 12xf4 = 48; rc dbuf 32; load transients 32;
// addressing ~14 -> ~126 <= 128 (arg2=2). E[chunks@J=12] = 1.07.
//
//   grid (8,128), 256 thr, thread = (c4 = tid&15: cols 4*c4..+3,
//   kq = tid>>4: rows kq*32..+31), NST=8 steps of 4 rows.
//   Per step: 4 W f4 + 4 D f4 (nt) loads issued for t+1, FMA(t) vs rc[cur],
//   then rc[nxt] combine (wait lands after FMA -> dist-1 preserved).
//   Epilogue: Red[8][12][16] f4 (24 KB, aliases Xs) in two kq-phases
//   (write kq<8, += kq>=8), then 192 threads sum 8 partials + bias,
//   nt store. LDS 28.4 KB; 16 waves/CU (VGPR-bound 4 waves/SIMD).

typedef float f32x4 __attribute__((ext_vector_type(4)));

__device__ __forceinline__ f32x4 nt_load4(const float* p) {
    return __builtin_nontemporal_load((const f32x4*)p);
}
__device__ __forceinline__ void nt_store4(float* p, f32x4 v) {
    __builtin_nontemporal_store(v, (f32x4*)p);
}

__global__ __launch_bounds__(256, 2) void lms_fused_nt_w4(
    const float* __restrict__ X, const int* __restrict__ head_ix,
    const int* __restrict__ split_ix, const float* __restrict__ W,
    const float* __restrict__ D, const float* __restrict__ bias,
    float* __restrict__ out)
{
    constexpr int J    = 12;           // samples per chunk (E[chunks]=1.07)
    constexpr int KQ   = 16;           // k-split ways
    constexpr int KT   = IN_F / KQ;    // 32 k rows per thread
    constexpr int NST  = KT / 4;       // 8 steps of 4 rows

    __shared__ float buf[J * IN_F];    // Xs[12][512] <-> Red[8][12][16] f4
    __shared__ int   list[N_SAMP];
    __shared__ int   wsum[4];

    const int g    = blockIdx.y;           // combo = h*N_SPLITS + s
    const int h    = g >> 2;               // N_SPLITS == 4
    const int c0   = blockIdx.x * 64;
    const int tid  = threadIdx.x;
    const int c4   = tid & 15;             // col-quad: cols c0+4*c4 .. +3
    const int kq   = tid >> 4;             // k-sixteenth (0..15)
    const int lane = tid & 63;
    const int wave = tid >> 6;

    // deterministic order-preserving compaction of samples matching combo g
    int run = 0;
    for (int r = 0; r < N_SAMP / 256; ++r) {
        const int i   = r * 256 + tid;
        const int key = head_ix[i] * N_SPLITS + split_ix[i];
        const bool hit = (key == g);
        const unsigned long long m = __ballot(hit);
        if (lane == 0) wsum[wave] = __popcll(m);
        __syncthreads();
        int base = run;
        for (int w = 0; w < 4; ++w)
            if (w < wave) base += wsum[w];
        if (hit)
            list[base + __popcll(m & ((1ULL << lane) - 1ULL))] = i;
        run += wsum[0] + wsum[1] + wsum[2] + wsum[3];
        __syncthreads();               // wsum consumed before next round
    }
    const int total = run;
    if (total == 0) return;            // block-uniform

    // thread's stripes: rows kq*KT .. kq*KT+31, cols c0+4*c4 .. +3
    const size_t roff = (size_t)(kq * KT) * OUT_F + c0 + c4 * 4;
    const float* wp = W + (size_t)h * (IN_F * OUT_F) + roff;
    const float* dp = D + (size_t)g * (IN_F * OUT_F) + roff;

    for (int s0 = 0; s0 < total; s0 += J) {
        const int nc = min(total - s0, J);

        __syncthreads();               // buf may still hold previous Red
        // stage Xs: J*128 = 1536 float4 over 256 threads = 6 each
#pragma unroll
        for (int f = 0; f < 6; ++f) {
            const int i = f * 256 + tid;       // 0..1535
            const int s = i >> 7, q = i & 127;
            float4 v = make_float4(0.f, 0.f, 0.f, 0.f);
            if (s < nc)
                v = *(const float4*)(X + (size_t)list[s0 + s] * IN_F + q * 4);
            *(float4*)(&buf[s * IN_F + q * 4]) = v;
        }
        __syncthreads();

        f32x4 acc[J];
#pragma unroll
        for (int j = 0; j < J; ++j) acc[j] = (f32x4)0.f;

        // dist-1 pipeline on combined rc (f4): issue loads(t+1) -> FMA(t)
        // -> rc[nxt] = combine (vmcnt wait lands after the FMA block)
        f32x4 rc[2][4];
        {
            // prolog: loads(0) + rc[0]
            f32x4 w0[4], d0[4];
#pragma unroll
            for (int u = 0; u < 4; ++u) {
                w0[u] = *(const f32x4*)(wp + (size_t)u * OUT_F);
                d0[u] = nt_load4(dp + (size_t)u * OUT_F);
            }
#pragma unroll
            for (int u = 0; u < 4; ++u)
                rc[0][u] = w0[u] + DELTA_SCALE * d0[u];
        }

#pragma unroll
        for (int st = 0; st < NST; ++st) {
            const int cb = st & 1, nb = cb ^ 1;
            // issue loads for t+1 (clamped tail: redundant L1-hit re-load
            // keeps the body branch-free)
            const int nr = (st + 1 < NST) ? (st + 1) * 4 : st * 4;
            f32x4 wl[4], dl[4];
#pragma unroll
            for (int u = 0; u < 4; ++u) {
                wl[u] = *(const f32x4*)(wp + (size_t)(nr + u) * OUT_F);
                dl[u] = nt_load4(dp + (size_t)(nr + u) * OUT_F);
            }

            // FMA(t) against rc[cb] -- no dependence on wl/dl
            const float* xb = &buf[kq * KT + st * 4];
#pragma unroll
            for (int j = 0; j < J; ++j) {
                const float4 xv = *(const float4*)(xb + j * IN_F); // broadcast
                acc[j] += xv.x * rc[cb][0];
                acc[j] += xv.y * rc[cb][1];
                acc[j] += xv.z * rc[cb][2];
                acc[j] += xv.w * rc[cb][3];
            }

            // combine for t+1 (first use of wl/dl -> wait sits here)
#pragma unroll
            for (int u = 0; u < 4; ++u)
                rc[nb][u] = wl[u] + DELTA_SCALE * dl[u];
        }

        // ---- epilogue: two-phase k-reduction through 24 KB Red ----
        __syncthreads();               // Xs fully consumed; reuse buf as Red
        f32x4* Red = (f32x4*)buf;      // [8][J][16]
        if (kq < 8) {
#pragma unroll
            for (int j = 0; j < J; ++j)
                Red[(kq * J + j) * 16 + c4] = acc[j];
        }
        __syncthreads();
        if (kq >= 8) {
            const int q = kq - 8;
#pragma unroll
            for (int j = 0; j < J; ++j) {
                f32x4 r = Red[(q * J + j) * 16 + c4];
                Red[(q * J + j) * 16 + c4] = r + acc[j];
            }
        }
        __syncthreads();

        // sole-owner: 192 threads sum the 8 partials, add bias, nt store
        if (tid < J * 16) {
            const int j  = tid >> 4;       // 0..11
            const int cc = tid & 15;
            if (j < nc) {
                f32x4 s = (f32x4)0.f;
#pragma unroll
                for (int q = 0; q < 8; ++q)
                    s += Red[(q * J + j) * 16 + cc];
                const f32x4 bv = *(const f32x4*)(bias + (size_t)h * OUT_F
                                                 + c0 + cc * 4);
                float* op = out + (size_t)list[s0 + j] * OUT_F + c0 + cc * 4;
                nt_store4(op, s + bv);
            }
        }
    }
}

extern "C" void kernel_launch(void* const* d_in, const int* in_sizes, int n_in,
                              void* d_out, int out_size, void* d_ws, size_t ws_size,
                              hipStream_t stream) {
    const float* X        = (const float*)d_in[0];
    const int*   head_ix  = (const int*)d_in[1];
    const int*   split_ix = (const int*)d_in[2];
    const float* W        = (const float*)d_in[3];
    const float* D        = (const float*)d_in[4];
    const float* bias     = (const float*)d_in[5];
    float*       out      = (float*)d_out;

    // 128 combos x 8 col-tiles = 1024 blocks of 256 thr. LDS 28.4 KB;
    // launch_bounds(256,2) -> VGPR cap 128 (budget ~126). Runtime: 4
    // blocks/CU x 4 waves = 16 waves/CU (VGPR-bound). Single dispatch.
    dim3 gf(OUT_F / 64, N_GROUPS);
    lms_fused_nt_w4<<<gf, 256, 0, stream>>>(X, head_ix, split_ix, W, D, bias, out);
}